// Round 17
// baseline (118.775 us; speedup 1.0000x reference)
//
#include <hip/hip_runtime.h>
#include <hip/hip_bf16.h>
#include <cstdint>

typedef __attribute__((ext_vector_type(8))) short short8;
typedef __attribute__((ext_vector_type(4))) short short4v;
typedef __attribute__((ext_vector_type(4))) float f32x4;

static constexpr int HWPIX = 16384;   // 128*128
static constexpr int NCH   = 512;
static constexpr int GCHK  = 32;      // gram pixel chunks (512 px each)

__device__ __forceinline__ unsigned short f2bf(float f) {
    unsigned int u = __float_as_uint(f);
    u = (u + 0x7fffu + ((u >> 16) & 1u)) >> 16;
    return (unsigned short)u;
}

// Conv: 64co x 128px (one image row) per block; kh in sections of 8 input rows.
// K-dim per section: kw outer, icr = ic*8 + rr inner; SROW = 24.
// B elem offset = col*24 + seg*8 -> linear in chunk t, no division in loop.
// r17: 2x2 WAVE SPLIT -- wave (kq,pq): kq owns chunks t = kq, kq+2, ...;
// pq owns px half pq*64..+64. acc = 64 AGPR -> ~150 unified regs ->
// 3 waves/SIMD (launch_bounds(256,3)); A-chunk read by both pq waves (L1 hit).
// Staging/grid/barriers identical to the proven r10/r16 structure.
template<int K> struct KG {
    static constexpr int P     = (K - 1) / 2;
    static constexpr int NSEC  = (K + 7) / 8;          // kh sections
    static constexpr int SEGS  = 3 * K;                // octet-segments per section
    static constexpr int NCHK  = (SEGS + 3) / 4;       // MFMA K-32 chunks per section
    static constexpr int NCHKP = ((NCHK + 3) / 4) * 4; // padded (multiple of 4, even)
    static constexpr int COLS  = 128 + K - 1;
    static constexpr int XPAD  = 128;
    static constexpr int XSE   = COLS * 24 + XPAD;
};
// max padded seg read: 127*24 + (NCHKP-1)*32 + lg*8max24 + 8 inside XSE
static_assert(127 * 24 + (KG<55>::NCHKP * 4 - 1) * 8 + 8 <= KG<55>::XSE, "pad55");
static_assert(127 * 24 + (KG<11>::NCHKP * 4 - 1) * 8 + 8 <= KG<11>::XSE, "pad11");
static_assert(KG<55>::XSE * 2 <= 18432, "xs fits smem");
static_assert(2 * 2 * 64 * 18 * 4 <= 18432, "red fits smem");

struct PtrArgs {
    const float* w[8];
    const float* bias[8];
    unsigned short* wpk[8];
    int cum[9];            // cumulative NSEC*NCHKP per filter
};

// ---------------- weight repack (unchanged layout) ----------------
template<int K>
__device__ void repack_body(const float* __restrict__ w, unsigned short* __restrict__ wpk, int t) {
    constexpr int NCHKP = KG<K>::NCHKP;
    const int sec = t / NCHKP;
    const int tc  = t - sec * NCHKP;
    const int tid = threadIdx.x;
    const int co  = ((tid >> 6) << 4) + (tid & 15);
    const int seg = tc * 4 + ((tid >> 4) & 3);
    int kw = 0, r = 0;
    const bool vseg = seg < KG<K>::SEGS;
    if (vseg) { kw = seg / 3; r = seg - kw * 3; }
    short8 o;
    #pragma unroll
    for (int j = 0; j < 8; ++j) {
        const int icr = r * 8 + j;
        const int ic  = icr >> 3;
        const int kh  = sec * 8 + (icr & 7);
        float v = 0.f;
        if (vseg && kh < K)
            v = w[((co * 3 + ic) * K + kh) * K + kw];
        o[j] = (short)f2bf(v);
    }
    *reinterpret_cast<short8*>(wpk + ((size_t)(t * 256 + tid)) * 8) = o;
}

__global__ __launch_bounds__(256) void repack_all(PtrArgs a) {
    const int blk = blockIdx.x;
    int f = 0;
    #pragma unroll
    for (int i = 0; i < 8; ++i) if (blk >= a.cum[i + 1]) f = i + 1;
    const int t = blk - a.cum[f];
    switch (f) {
        case 0: repack_body< 3>(a.w[0], a.wpk[0], t); break;
        case 1: repack_body< 5>(a.w[1], a.wpk[1], t); break;
        case 2: repack_body< 7>(a.w[2], a.wpk[2], t); break;
        case 3: repack_body<11>(a.w[3], a.wpk[3], t); break;
        case 4: repack_body<15>(a.w[4], a.wpk[4], t); break;
        case 5: repack_body<23>(a.w[5], a.wpk[5], t); break;
        case 6: repack_body<37>(a.w[6], a.wpk[6], t); break;
        case 7: repack_body<55>(a.w[7], a.wpk[7], t); break;
    }
}

// -- conv: 256 thr, 4 waves = 2(K-half) x 2(px-half); wave = 64co x 64px --
#define MFMA_BF16 __builtin_amdgcn_mfma_f32_16x16x32_bf16

template<int K>
__device__ void conv_body(const float* __restrict__ x, const unsigned short* __restrict__ wpk,
                          const float* __restrict__ bias, unsigned short* __restrict__ feat,
                          int cbase, char* smem, int bx)
{
    constexpr int P     = KG<K>::P;
    constexpr int NCHKP = KG<K>::NCHKP;
    constexpr int NSEC  = KG<K>::NSEC;
    constexpr int COLS  = KG<K>::COLS;

    unsigned short* xs = (unsigned short*)smem;
    float* red = (float*)smem;          // aliases xs; used only after xs is dead

    const int tid = threadIdx.x;
    const int b   = bx >> 7;            // batch
    const int h   = bx & 127;           // image row

    const int lane = tid & 63;
    const int wv   = tid >> 6;          // 0..3
    const int kq   = wv >> 1;           // K-half: chunks t = kq, kq+2, ...
    const int pq   = wv & 1;            // px half: cols pq*64 .. +64
    const int ln15 = lane & 15;
    const int lg   = lane >> 4;         // k-octet 0..3

    // zero the pad region (tail-seg reads land here; stays zero while xs lives)
    for (int i = tid * 4; i < KG<K>::XPAD; i += 1024)
        *reinterpret_cast<short4v*>(xs + COLS * 24 + i) = short4v{0, 0, 0, 0};

    f32x4 acc[4][4] = {};               // [costrip][pxfrag of 16]
    const float* xb = x + (size_t)b * 3 * HWPIX;

    for (int sec = 0; sec < NSEC; ++sec) {
        if (sec > 0) __syncthreads();   // all waves done reading previous section
        for (int e = tid * 4; e < 24 * COLS; e += 1024) {
            const int c  = e / 24;
            const int i0 = e - c * 24;
            const int col = c - P;
            short4v pk;
            #pragma unroll
            for (int j = 0; j < 4; ++j) {
                const int icr = i0 + j;
                const int ic  = icr >> 3;
                const int row = h + sec * 8 + (icr & 7) - P;
                float v = 0.f;
                if ((unsigned)row < 128u && (unsigned)col < 128u)
                    v = xb[ic * HWPIX + row * 128 + col];
                pk[j] = (short)f2bf(v);
            }
            *reinterpret_cast<short4v*>(xs + e) = pk;
        }
        __syncthreads();

        const unsigned short* ws = wpk + (size_t)sec * NCHKP * 2048 + lane * 8;
        for (int tt = 0; tt < NCHKP / 2; ++tt) {
            const int t = tt * 2 + kq;
            const unsigned short* ap = ws + (size_t)t * 2048;
            short8 a0 = *reinterpret_cast<const short8*>(ap);
            short8 a1 = *reinterpret_cast<const short8*>(ap + 512);
            short8 a2 = *reinterpret_cast<const short8*>(ap + 1024);
            short8 a3 = *reinterpret_cast<const short8*>(ap + 1536);
            const unsigned short* bp = xs + (pq * 64 + ln15) * 24 + lg * 8 + t * 32;
            short8 b0 = *reinterpret_cast<const short8*>(bp);
            short8 b1 = *reinterpret_cast<const short8*>(bp + 1 * 384);
            short8 b2 = *reinterpret_cast<const short8*>(bp + 2 * 384);
            short8 b3 = *reinterpret_cast<const short8*>(bp + 3 * 384);

            acc[0][0] = MFMA_BF16(a0, b0, acc[0][0], 0, 0, 0);
            acc[0][1] = MFMA_BF16(a0, b1, acc[0][1], 0, 0, 0);
            acc[0][2] = MFMA_BF16(a0, b2, acc[0][2], 0, 0, 0);
            acc[0][3] = MFMA_BF16(a0, b3, acc[0][3], 0, 0, 0);
            acc[1][0] = MFMA_BF16(a1, b0, acc[1][0], 0, 0, 0);
            acc[1][1] = MFMA_BF16(a1, b1, acc[1][1], 0, 0, 0);
            acc[1][2] = MFMA_BF16(a1, b2, acc[1][2], 0, 0, 0);
            acc[1][3] = MFMA_BF16(a1, b3, acc[1][3], 0, 0, 0);
            acc[2][0] = MFMA_BF16(a2, b0, acc[2][0], 0, 0, 0);
            acc[2][1] = MFMA_BF16(a2, b1, acc[2][1], 0, 0, 0);
            acc[2][2] = MFMA_BF16(a2, b2, acc[2][2], 0, 0, 0);
            acc[2][3] = MFMA_BF16(a2, b3, acc[2][3], 0, 0, 0);
            acc[3][0] = MFMA_BF16(a3, b0, acc[3][0], 0, 0, 0);
            acc[3][1] = MFMA_BF16(a3, b1, acc[3][1], 0, 0, 0);
            acc[3][2] = MFMA_BF16(a3, b2, acc[3][2], 0, 0, 0);
            acc[3][3] = MFMA_BF16(a3, b3, acc[3][3], 0, 0, 0);
        }
    }

    // ---- cross-wave reduction via LDS: sum kq=0,1 per px-half ----
    __syncthreads();
    const float bv  = bias[tid >> 2];
    const int   eco = tid >> 2;          // 0..63
    const int   ep0 = (tid & 3) * 4;     // 0,4,8,12
    const size_t fbase = (((size_t)(b * NCH + cbase + eco)) << 14) + h * 128;

    #pragma unroll
    for (int q = 0; q < 4; ++q) {
        if (q > 0) __syncthreads();      // previous pass's reads done
        #pragma unroll
        for (int cs = 0; cs < 4; ++cs)
            #pragma unroll
            for (int i = 0; i < 4; ++i)
                red[pq * 2304 + (kq * 64 + cs * 16 + lg * 4 + i) * 18 + ln15] = acc[cs][q][i];
        __syncthreads();
        #pragma unroll
        for (int half = 0; half < 2; ++half) {
            short4v o;
            #pragma unroll
            for (int j = 0; j < 4; ++j) {
                const int px = ep0 + j;
                float v = red[half * 2304 + eco * 18 + px]
                        + red[half * 2304 + (64 + eco) * 18 + px];
                o[j] = (short)f2bf(fmaxf(v + bv, 0.f));
            }
            *reinterpret_cast<short4v*>(feat + fbase + half * 64 + q * 16 + ep0) = o;
        }
    }
}

__global__ __launch_bounds__(256, 3) void conv_all(const float* __restrict__ x,
                                                   PtrArgs a, unsigned short* __restrict__ feat)
{
    __shared__ __align__(16) char smem[18432];   // max(xs 8992B, red 18432B)
    // LPT dispatch: heaviest filter (K=55) first so it spreads over all CUs
    switch (7 - blockIdx.y) {
        case 0: conv_body< 3>(x, a.wpk[0], a.bias[0], feat, 0 * 64, smem, blockIdx.x); break;
        case 1: conv_body< 5>(x, a.wpk[1], a.bias[1], feat, 1 * 64, smem, blockIdx.x); break;
        case 2: conv_body< 7>(x, a.wpk[2], a.bias[2], feat, 2 * 64, smem, blockIdx.x); break;
        case 3: conv_body<11>(x, a.wpk[3], a.bias[3], feat, 3 * 64, smem, blockIdx.x); break;
        case 4: conv_body<15>(x, a.wpk[4], a.bias[4], feat, 4 * 64, smem, blockIdx.x); break;
        case 5: conv_body<23>(x, a.wpk[5], a.bias[5], feat, 5 * 64, smem, blockIdx.x); break;
        case 6: conv_body<37>(x, a.wpk[6], a.bias[6], feat, 6 * 64, smem, blockIdx.x); break;
        case 7: conv_body<55>(x, a.wpk[7], a.bias[7], feat, 7 * 64, smem, blockIdx.x); break;
    }
}

// ---------------- gram via MFMA (unchanged, passing since r4) ----------------
__global__ __launch_bounds__(256) void gram_mfma(
    const unsigned short* __restrict__ feat, const int* __restrict__ perm,
    float* __restrict__ part)
{
    __shared__ __align__(16) unsigned short tile[64 * 256];
    __shared__ int permch[64];

    const int bg = blockIdx.y, chunk = blockIdx.x;
    const int b = bg >> 3, gq = bg & 7;
    const int tid = threadIdx.x;

    if (tid < 64) permch[tid] = perm[gq * 64 + tid];
    __syncthreads();

    const int lane = tid & 63;
    const int wv   = tid >> 6;
    const int ln15 = lane & 15;
    const int kg   = lane >> 4;

    f32x4 acc[4] = {};
    const size_t pxbase = (size_t)chunk * 512;

    for (int p2 = 0; p2 < 2; ++p2) {
        {
            const int r0 = tid >> 5;        // 0..7
            const int g  = tid & 31;        // 16B group 0..31
            #pragma unroll
            for (int it = 0; it < 8; ++it) {
                const int r = it * 8 + r0;
                const unsigned short* src =
                    feat + (((size_t)(b * NCH + permch[r])) << 14) + pxbase + p2 * 256 + g * 8;
                short8 v = *reinterpret_cast<const short8*>(src);
                *reinterpret_cast<short8*>(tile + r * 256 + ((g ^ (r & 7)) * 8)) = v;
            }
        }
        __syncthreads();
        #pragma unroll
        for (int t = 0; t < 8; ++t) {
            const int g  = t * 4 + kg;
            const int ra = wv * 16 + ln15;
            short8 av = *reinterpret_cast<const short8*>(tile + ra * 256 + ((g ^ (ra & 7)) * 8));
            #pragma unroll
            for (int cs = 0; cs < 4; ++cs) {
                const int rb = cs * 16 + ln15;
                short8 bv = *reinterpret_cast<const short8*>(tile + rb * 256 + ((g ^ (rb & 7)) * 8));
                acc[cs] = MFMA_BF16(av, bv, acc[cs], 0, 0, 0);
            }
        }
        __syncthreads();
    }

    float* pp = part + ((size_t)bg * GCHK + chunk) * 4096;
    #pragma unroll
    for (int cs = 0; cs < 4; ++cs)
        #pragma unroll
        for (int i = 0; i < 4; ++i) {
            const int row = wv * 16 + kg * 4 + i;
            const int col = cs * 16 + ln15;
            pp[row * 64 + col] = acc[cs][i];
        }
}

__global__ __launch_bounds__(256) void gram_reduce(
    const float* __restrict__ part, float* __restrict__ out)
{
    const int idx = blockIdx.x * 256 + threadIdx.x;   // 0..65535
    const int bg  = idx >> 12;
    const int e   = idx & 4095;
    const float* p = part + (size_t)bg * GCHK * 4096 + e;
    float s = 0.f;
    #pragma unroll
    for (int c = 0; c < GCHK; ++c) s += p[c * 4096];
    out[idx] = s;
}

extern "C" void kernel_launch(void* const* d_in, const int* in_sizes, int n_in,
                              void* d_out, int out_size, void* d_ws, size_t ws_size,
                              hipStream_t stream) {
    const float* x = (const float*)d_in[0];
    const int* perm = (const int*)d_in[17];

    // ws: feat bf16 32MiB | part 8MiB | wpk 572 chunks * 4KiB = 2.29MiB
    unsigned short* feat = (unsigned short*)d_ws;
    float* part = (float*)((char*)d_ws + (size_t)2 * NCH * HWPIX * sizeof(unsigned short));
    unsigned short* wpk0 = (unsigned short*)((char*)part + (size_t)16 * GCHK * 4096 * sizeof(float));
    float* out = (float*)d_out;

    const int nchk[8] = { KG<3>::NSEC * KG<3>::NCHKP,  KG<5>::NSEC * KG<5>::NCHKP,
                          KG<7>::NSEC * KG<7>::NCHKP,  KG<11>::NSEC * KG<11>::NCHKP,
                          KG<15>::NSEC * KG<15>::NCHKP, KG<23>::NSEC * KG<23>::NCHKP,
                          KG<37>::NSEC * KG<37>::NCHKP, KG<55>::NSEC * KG<55>::NCHKP };
    PtrArgs a;
    int acc = 0;
    for (int i = 0; i < 8; ++i) {
        a.w[i]    = (const float*)d_in[1 + 2 * i];
        a.bias[i] = (const float*)d_in[2 + 2 * i];
        a.wpk[i]  = wpk0 + (size_t)acc * 2048;
        a.cum[i]  = acc;
        acc += nchk[i];
    }
    a.cum[8] = acc;   // 572 total chunk-sections

    repack_all<<<acc, 256, 0, stream>>>(a);
    conv_all<<<dim3(256, 8), 256, 0, stream>>>(x, a, feat);
    gram_mfma<<<dim3(GCHK, 16), 256, 0, stream>>>(feat, perm, part);
    gram_reduce<<<dim3(65536 / 256), 256, 0, stream>>>(part, out);
}

// Round 18
// 115.128 us; speedup vs baseline: 1.0317x; 1.0317x over previous
//
#include <hip/hip_runtime.h>
#include <hip/hip_bf16.h>
#include <cstdint>

typedef __attribute__((ext_vector_type(8))) short short8;
typedef __attribute__((ext_vector_type(4))) short short4v;
typedef __attribute__((ext_vector_type(4))) float f32x4;

static constexpr int HWPIX = 16384;   // 128*128
static constexpr int NCH   = 512;
static constexpr int GCHK  = 32;      // gram pixel chunks (512 px each)
// padded bf16 image: [b][ic][184 rows][192 cols], image origin at (27,27)
static constexpr int XPH = 184, XPW = 192, XPOFF = 27;
static constexpr int XPELEMS = 2 * 3 * XPH * XPW;

__device__ __forceinline__ unsigned short f2bf(float f) {
    unsigned int u = __float_as_uint(f);
    u = (u + 0x7fffu + ((u >> 16) & 1u)) >> 16;
    return (unsigned short)u;
}

// Conv: 64co x 128px (one image row) per block; kh in sections of 8 input rows.
// K-dim per section: kw outer, icr = ic*8 + rr inner; SROW = 24.
// B elem offset = col*24 + seg*8 -> linear in seg, no div in the MFMA loop.
// K-SPLIT (r10/r16 proven): wave w owns chunks t = w, w+4, ...; computes the
// FULL 64co x 128px tile for its chunks. f32 cross-wave reduce via LDS.
// r18: staging reads the PRE-PADDED bf16 image -> no bounds checks, no f2bf
// on the stage critical path (was ~8 VALU/elem -> ~3).
template<int K> struct KG {
    static constexpr int P     = (K - 1) / 2;
    static constexpr int NSEC  = (K + 7) / 8;          // kh sections
    static constexpr int SEGS  = 3 * K;                // octet-segments per section
    static constexpr int NCHK  = (SEGS + 3) / 4;       // MFMA K-32 chunks per section
    static constexpr int NCHKP = ((NCHK + 3) / 4) * 4; // padded to 4 waves
    static constexpr int COLS  = 128 + K - 1;
    static constexpr int XPAD  = 128;
    static constexpr int XSE   = COLS * 24 + XPAD;
    // xpad access bounds (stage): row idx = h + sec*8 + rr - P + 27 <= 182
    static constexpr int RMAX  = 127 + (NSEC * 8 - 1) - P + XPOFF;
    static constexpr int CMAX  = (COLS - 1) - P + XPOFF;
};
static_assert(KG<55>::RMAX < XPH && KG<55>::CMAX < XPW, "xpad55");
static_assert(KG<37>::RMAX < XPH && KG<37>::CMAX < XPW, "xpad37");
static_assert(KG<23>::RMAX < XPH && KG<23>::CMAX < XPW, "xpad23");
static_assert(KG<15>::RMAX < XPH && KG<15>::CMAX < XPW, "xpad15");
static_assert(KG<11>::RMAX < XPH && KG<11>::CMAX < XPW, "xpad11");
static_assert(KG< 7>::RMAX < XPH && KG< 7>::CMAX < XPW, "xpad7");
static_assert(KG< 5>::RMAX < XPH && KG< 5>::CMAX < XPW, "xpad5");
static_assert(KG< 3>::RMAX < XPH && KG< 3>::CMAX < XPW, "xpad3");
// max padded seg read inside XSE
static_assert(127 * 24 + (KG<55>::NCHKP * 4 - 1) * 8 + 8 <= KG<55>::XSE, "pad55");
static_assert(127 * 24 + (KG<11>::NCHKP * 4 - 1) * 8 + 8 <= KG<11>::XSE, "pad11");
static_assert(KG<55>::XSE * 2 <= 18432, "xs fits smem");

struct PtrArgs {
    const float* w[8];
    const float* bias[8];
    unsigned short* wpk[8];
    int cum[9];            // cumulative NSEC*NCHKP per filter
};

// ---------------- input pre-pad: f32 image -> zero-bordered bf16 ----------------
__global__ __launch_bounds__(256) void prepad(const float* __restrict__ x,
                                              unsigned short* __restrict__ xpad)
{
    const int idx = blockIdx.x * 256 + threadIdx.x;
    if (idx >= XPELEMS) return;
    const int cidx = idx % XPW;
    const int t1   = idx / XPW;
    const int r    = t1 % XPH;
    const int bc   = t1 / XPH;          // b*3 + ic
    const int row = r - XPOFF, col = cidx - XPOFF;
    float v = 0.f;
    if ((unsigned)row < 128u && (unsigned)col < 128u)
        v = x[(size_t)bc * HWPIX + row * 128 + col];
    xpad[idx] = f2bf(v);
}

// ---------------- weight repack (unchanged layout) ----------------
template<int K>
__device__ void repack_body(const float* __restrict__ w, unsigned short* __restrict__ wpk, int t) {
    constexpr int NCHKP = KG<K>::NCHKP;
    const int sec = t / NCHKP;
    const int tc  = t - sec * NCHKP;
    const int tid = threadIdx.x;
    const int co  = ((tid >> 6) << 4) + (tid & 15);
    const int seg = tc * 4 + ((tid >> 4) & 3);
    int kw = 0, r = 0;
    const bool vseg = seg < KG<K>::SEGS;
    if (vseg) { kw = seg / 3; r = seg - kw * 3; }
    short8 o;
    #pragma unroll
    for (int j = 0; j < 8; ++j) {
        const int icr = r * 8 + j;
        const int ic  = icr >> 3;
        const int kh  = sec * 8 + (icr & 7);
        float v = 0.f;
        if (vseg && kh < K)
            v = w[((co * 3 + ic) * K + kh) * K + kw];
        o[j] = (short)f2bf(v);
    }
    *reinterpret_cast<short8*>(wpk + ((size_t)(t * 256 + tid)) * 8) = o;
}

__global__ __launch_bounds__(256) void repack_all(PtrArgs a) {
    const int blk = blockIdx.x;
    int f = 0;
    #pragma unroll
    for (int i = 0; i < 8; ++i) if (blk >= a.cum[i + 1]) f = i + 1;
    const int t = blk - a.cum[f];
    switch (f) {
        case 0: repack_body< 3>(a.w[0], a.wpk[0], t); break;
        case 1: repack_body< 5>(a.w[1], a.wpk[1], t); break;
        case 2: repack_body< 7>(a.w[2], a.wpk[2], t); break;
        case 3: repack_body<11>(a.w[3], a.wpk[3], t); break;
        case 4: repack_body<15>(a.w[4], a.wpk[4], t); break;
        case 5: repack_body<23>(a.w[5], a.wpk[5], t); break;
        case 6: repack_body<37>(a.w[6], a.wpk[6], t); break;
        case 7: repack_body<55>(a.w[7], a.wpk[7], t); break;
    }
}

// -------- conv: 256 thr, 4 waves; wave = 64co x 128px x (1/4 of K-chunks) --------
#define MFMA_BF16 __builtin_amdgcn_mfma_f32_16x16x32_bf16

template<int K>
__device__ void conv_body(const unsigned short* __restrict__ xpad,
                          const unsigned short* __restrict__ wpk,
                          const float* __restrict__ bias, unsigned short* __restrict__ feat,
                          int cbase, char* smem, int bx)
{
    constexpr int P     = KG<K>::P;
    constexpr int NCHKP = KG<K>::NCHKP;
    constexpr int NSEC  = KG<K>::NSEC;
    constexpr int COLS  = KG<K>::COLS;

    unsigned short* xs = (unsigned short*)smem;
    float* red = (float*)smem;          // aliases xs; used only after xs is dead

    const int tid = threadIdx.x;
    const int b   = bx >> 7;            // batch
    const int h   = bx & 127;           // image row

    const int lane = tid & 63;
    const int wv   = tid >> 6;          // 0..3 -> K-chunk quarter
    const int ln15 = lane & 15;
    const int lg   = lane >> 4;         // k-octet 0..3

    // zero the pad region (tail-seg reads land here; stays zero while xs lives)
    for (int i = tid * 4; i < KG<K>::XPAD; i += 1024)
        *reinterpret_cast<short4v*>(xs + COLS * 24 + i) = short4v{0, 0, 0, 0};

    f32x4 acc[4][8] = {};               // [costrip][pxstrip]
    const unsigned short* xpb = xpad + (size_t)b * 3 * XPH * XPW;

    for (int sec = 0; sec < NSEC; ++sec) {
        if (sec > 0) __syncthreads();   // all waves done reading previous section
        // stage: branch-free bf16 copy from the pre-padded image
        {
            const unsigned short* secbase =
                xpb + (h + sec * 8 - P + XPOFF) * XPW + (XPOFF - P);
            for (int e = tid * 4; e < 24 * COLS; e += 1024) {
                const int c  = e / 24;
                const int i0 = e - c * 24;
                short4v pk;
                #pragma unroll
                for (int j = 0; j < 4; ++j) {
                    const int icr = i0 + j;
                    pk[j] = (short)secbase[((icr >> 3) * XPH + (icr & 7)) * XPW + c];
                }
                *reinterpret_cast<short4v*>(xs + e) = pk;
            }
        }
        __syncthreads();

        const unsigned short* ws = wpk + (size_t)sec * NCHKP * 2048 + lane * 8;
        for (int tt = 0; tt < NCHKP / 4; ++tt) {
            const int t = tt * 4 + wv;
            const unsigned short* ap = ws + (size_t)t * 2048;
            short8 a0 = *reinterpret_cast<const short8*>(ap);
            short8 a1 = *reinterpret_cast<const short8*>(ap + 512);
            short8 a2 = *reinterpret_cast<const short8*>(ap + 1024);
            short8 a3 = *reinterpret_cast<const short8*>(ap + 1536);
            const unsigned short* bp = xs + ln15 * 24 + lg * 8 + t * 32;
            short8 b0 = *reinterpret_cast<const short8*>(bp);
            short8 b1 = *reinterpret_cast<const short8*>(bp + 1 * 384);
            short8 b2 = *reinterpret_cast<const short8*>(bp + 2 * 384);
            short8 b3 = *reinterpret_cast<const short8*>(bp + 3 * 384);
            short8 b4 = *reinterpret_cast<const short8*>(bp + 4 * 384);
            short8 b5 = *reinterpret_cast<const short8*>(bp + 5 * 384);
            short8 b6 = *reinterpret_cast<const short8*>(bp + 6 * 384);
            short8 b7 = *reinterpret_cast<const short8*>(bp + 7 * 384);

            acc[0][0] = MFMA_BF16(a0, b0, acc[0][0], 0, 0, 0);
            acc[0][1] = MFMA_BF16(a0, b1, acc[0][1], 0, 0, 0);
            acc[0][2] = MFMA_BF16(a0, b2, acc[0][2], 0, 0, 0);
            acc[0][3] = MFMA_BF16(a0, b3, acc[0][3], 0, 0, 0);
            acc[0][4] = MFMA_BF16(a0, b4, acc[0][4], 0, 0, 0);
            acc[0][5] = MFMA_BF16(a0, b5, acc[0][5], 0, 0, 0);
            acc[0][6] = MFMA_BF16(a0, b6, acc[0][6], 0, 0, 0);
            acc[0][7] = MFMA_BF16(a0, b7, acc[0][7], 0, 0, 0);
            acc[1][0] = MFMA_BF16(a1, b0, acc[1][0], 0, 0, 0);
            acc[1][1] = MFMA_BF16(a1, b1, acc[1][1], 0, 0, 0);
            acc[1][2] = MFMA_BF16(a1, b2, acc[1][2], 0, 0, 0);
            acc[1][3] = MFMA_BF16(a1, b3, acc[1][3], 0, 0, 0);
            acc[1][4] = MFMA_BF16(a1, b4, acc[1][4], 0, 0, 0);
            acc[1][5] = MFMA_BF16(a1, b5, acc[1][5], 0, 0, 0);
            acc[1][6] = MFMA_BF16(a1, b6, acc[1][6], 0, 0, 0);
            acc[1][7] = MFMA_BF16(a1, b7, acc[1][7], 0, 0, 0);
            acc[2][0] = MFMA_BF16(a2, b0, acc[2][0], 0, 0, 0);
            acc[2][1] = MFMA_BF16(a2, b1, acc[2][1], 0, 0, 0);
            acc[2][2] = MFMA_BF16(a2, b2, acc[2][2], 0, 0, 0);
            acc[2][3] = MFMA_BF16(a2, b3, acc[2][3], 0, 0, 0);
            acc[2][4] = MFMA_BF16(a2, b4, acc[2][4], 0, 0, 0);
            acc[2][5] = MFMA_BF16(a2, b5, acc[2][5], 0, 0, 0);
            acc[2][6] = MFMA_BF16(a2, b6, acc[2][6], 0, 0, 0);
            acc[2][7] = MFMA_BF16(a2, b7, acc[2][7], 0, 0, 0);
            acc[3][0] = MFMA_BF16(a3, b0, acc[3][0], 0, 0, 0);
            acc[3][1] = MFMA_BF16(a3, b1, acc[3][1], 0, 0, 0);
            acc[3][2] = MFMA_BF16(a3, b2, acc[3][2], 0, 0, 0);
            acc[3][3] = MFMA_BF16(a3, b3, acc[3][3], 0, 0, 0);
            acc[3][4] = MFMA_BF16(a3, b4, acc[3][4], 0, 0, 0);
            acc[3][5] = MFMA_BF16(a3, b5, acc[3][5], 0, 0, 0);
            acc[3][6] = MFMA_BF16(a3, b6, acc[3][6], 0, 0, 0);
            acc[3][7] = MFMA_BF16(a3, b7, acc[3][7], 0, 0, 0);
        }
    }

    // ---- cross-wave reduction via LDS (xs dead after this barrier) ----
    __syncthreads();
    const float bv  = bias[tid >> 2];
    const int   eco = tid >> 2;          // 0..63
    const int   ep0 = (tid & 3) * 4;     // 0,4,8,12
    const size_t fbase = (((size_t)(b * NCH + cbase + eco)) << 14) + h * 128;

    #pragma unroll
    for (int q = 0; q < 8; ++q) {
        if (q > 0) __syncthreads();      // previous pass's reads done
        #pragma unroll
        for (int cs = 0; cs < 4; ++cs)
            #pragma unroll
            for (int i = 0; i < 4; ++i)
                red[(wv * 64 + cs * 16 + lg * 4 + i) * 18 + ln15] = acc[cs][q][i];
        __syncthreads();
        short4v o;
        #pragma unroll
        for (int j = 0; j < 4; ++j) {
            const int px = ep0 + j;
            float v = red[(0 * 64 + eco) * 18 + px] + red[(1 * 64 + eco) * 18 + px]
                    + red[(2 * 64 + eco) * 18 + px] + red[(3 * 64 + eco) * 18 + px];
            o[j] = (short)f2bf(fmaxf(v + bv, 0.f));
        }
        *reinterpret_cast<short4v*>(feat + fbase + q * 16 + ep0) = o;
    }
}

__global__ __launch_bounds__(256, 2) void conv_all(const unsigned short* __restrict__ xpad,
                                                   PtrArgs a, unsigned short* __restrict__ feat)
{
    __shared__ __align__(16) char smem[18432];   // max(xs 8992B, red 4*64*18*4B)
    // LPT dispatch: heaviest filter (K=55) first so it spreads over all CUs
    switch (7 - blockIdx.y) {
        case 0: conv_body< 3>(xpad, a.wpk[0], a.bias[0], feat, 0 * 64, smem, blockIdx.x); break;
        case 1: conv_body< 5>(xpad, a.wpk[1], a.bias[1], feat, 1 * 64, smem, blockIdx.x); break;
        case 2: conv_body< 7>(xpad, a.wpk[2], a.bias[2], feat, 2 * 64, smem, blockIdx.x); break;
        case 3: conv_body<11>(xpad, a.wpk[3], a.bias[3], feat, 3 * 64, smem, blockIdx.x); break;
        case 4: conv_body<15>(xpad, a.wpk[4], a.bias[4], feat, 4 * 64, smem, blockIdx.x); break;
        case 5: conv_body<23>(xpad, a.wpk[5], a.bias[5], feat, 5 * 64, smem, blockIdx.x); break;
        case 6: conv_body<37>(xpad, a.wpk[6], a.bias[6], feat, 6 * 64, smem, blockIdx.x); break;
        case 7: conv_body<55>(xpad, a.wpk[7], a.bias[7], feat, 7 * 64, smem, blockIdx.x); break;
    }
}

// ---------------- gram via MFMA (unchanged, passing since r4) ----------------
__global__ __launch_bounds__(256) void gram_mfma(
    const unsigned short* __restrict__ feat, const int* __restrict__ perm,
    float* __restrict__ part)
{
    __shared__ __align__(16) unsigned short tile[64 * 256];
    __shared__ int permch[64];

    const int bg = blockIdx.y, chunk = blockIdx.x;
    const int b = bg >> 3, gq = bg & 7;
    const int tid = threadIdx.x;

    if (tid < 64) permch[tid] = perm[gq * 64 + tid];
    __syncthreads();

    const int lane = tid & 63;
    const int wv   = tid >> 6;
    const int ln15 = lane & 15;
    const int kg   = lane >> 4;

    f32x4 acc[4] = {};
    const size_t pxbase = (size_t)chunk * 512;

    for (int p2 = 0; p2 < 2; ++p2) {
        {
            const int r0 = tid >> 5;        // 0..7
            const int g  = tid & 31;        // 16B group 0..31
            #pragma unroll
            for (int it = 0; it < 8; ++it) {
                const int r = it * 8 + r0;
                const unsigned short* src =
                    feat + (((size_t)(b * NCH + permch[r])) << 14) + pxbase + p2 * 256 + g * 8;
                short8 v = *reinterpret_cast<const short8*>(src);
                *reinterpret_cast<short8*>(tile + r * 256 + ((g ^ (r & 7)) * 8)) = v;
            }
        }
        __syncthreads();
        #pragma unroll
        for (int t = 0; t < 8; ++t) {
            const int g  = t * 4 + kg;
            const int ra = wv * 16 + ln15;
            short8 av = *reinterpret_cast<const short8*>(tile + ra * 256 + ((g ^ (ra & 7)) * 8));
            #pragma unroll
            for (int cs = 0; cs < 4; ++cs) {
                const int rb = cs * 16 + ln15;
                short8 bv = *reinterpret_cast<const short8*>(tile + rb * 256 + ((g ^ (rb & 7)) * 8));
                acc[cs] = MFMA_BF16(av, bv, acc[cs], 0, 0, 0);
            }
        }
        __syncthreads();
    }

    float* pp = part + ((size_t)bg * GCHK + chunk) * 4096;
    #pragma unroll
    for (int cs = 0; cs < 4; ++cs)
        #pragma unroll
        for (int i = 0; i < 4; ++i) {
            const int row = wv * 16 + kg * 4 + i;
            const int col = cs * 16 + ln15;
            pp[row * 64 + col] = acc[cs][i];
        }
}

__global__ __launch_bounds__(256) void gram_reduce(
    const float* __restrict__ part, float* __restrict__ out)
{
    const int idx = blockIdx.x * 256 + threadIdx.x;   // 0..65535
    const int bg  = idx >> 12;
    const int e   = idx & 4095;
    const float* p = part + (size_t)bg * GCHK * 4096 + e;
    float s = 0.f;
    #pragma unroll
    for (int c = 0; c < GCHK; ++c) s += p[c * 4096];
    out[idx] = s;
}

extern "C" void kernel_launch(void* const* d_in, const int* in_sizes, int n_in,
                              void* d_out, int out_size, void* d_ws, size_t ws_size,
                              hipStream_t stream) {
    const float* x = (const float*)d_in[0];
    const int* perm = (const int*)d_in[17];

    // ws: feat bf16 32MiB | part 8MiB | wpk 572*4KiB = 2.29MiB | xpad 424KiB
    unsigned short* feat = (unsigned short*)d_ws;
    float* part = (float*)((char*)d_ws + (size_t)2 * NCH * HWPIX * sizeof(unsigned short));
    unsigned short* wpk0 = (unsigned short*)((char*)part + (size_t)16 * GCHK * 4096 * sizeof(float));
    unsigned short* xpad = wpk0 + (size_t)572 * 2048;
    float* out = (float*)d_out;

    const int nchk[8] = { KG<3>::NSEC * KG<3>::NCHKP,  KG<5>::NSEC * KG<5>::NCHKP,
                          KG<7>::NSEC * KG<7>::NCHKP,  KG<11>::NSEC * KG<11>::NCHKP,
                          KG<15>::NSEC * KG<15>::NCHKP, KG<23>::NSEC * KG<23>::NCHKP,
                          KG<37>::NSEC * KG<37>::NCHKP, KG<55>::NSEC * KG<55>::NCHKP };
    PtrArgs a;
    int acc = 0;
    for (int i = 0; i < 8; ++i) {
        a.w[i]    = (const float*)d_in[1 + 2 * i];
        a.bias[i] = (const float*)d_in[2 + 2 * i];
        a.wpk[i]  = wpk0 + (size_t)acc * 2048;
        a.cum[i]  = acc;
        acc += nchk[i];
    }
    a.cum[8] = acc;   // 572 total chunk-sections

    prepad<<<(XPELEMS + 255) / 256, 256, 0, stream>>>(x, xpad);
    repack_all<<<acc, 256, 0, stream>>>(a);
    conv_all<<<dim3(256, 8), 256, 0, stream>>>(xpad, a, feat);
    gram_mfma<<<dim3(GCHK, 16), 256, 0, stream>>>(feat, perm, part);
    gram_reduce<<<dim3(65536 / 256), 256, 0, stream>>>(part, out);
}

// Round 19
// 107.164 us; speedup vs baseline: 1.1083x; 1.0743x over previous
//
#include <hip/hip_runtime.h>
#include <hip/hip_bf16.h>
#include <cstdint>

typedef __attribute__((ext_vector_type(8))) short short8;
typedef __attribute__((ext_vector_type(4))) short short4v;
typedef __attribute__((ext_vector_type(4))) float f32x4;

static constexpr int HWPIX = 16384;   // 128*128
static constexpr int NCH   = 512;
static constexpr int GCHK  = 32;      // gram pixel chunks (512 px each)

__device__ __forceinline__ unsigned short f2bf(float f) {
    unsigned int u = __float_as_uint(f);
    u = (u + 0x7fffu + ((u >> 16) & 1u)) >> 16;
    return (unsigned short)u;
}

// Conv: 64co x 128px (one image row) per block; kh in sections of 8 input rows.
// K-dim per section: kw outer, icr = ic*8 + rr inner; SROW = 24.
// B elem offset = col*24 + seg*8 = (col+kw)*24 + r*8 -> linear in seg, no div.
// K-SPLIT: wave w handles chunks t = w, w+4, ...; each wave computes the FULL
// 64co x 128px tile for its chunks -> 4x less A traffic, 32 MFMAs per 4KB
// A-chunk. f32 partials reduced via LDS.
// FINAL (r19 = r16 = r10): best of 11 measured variants (conv 92us, MfmaUtil
// 33%). r11-r18 variants (occupancy 2/3 waves, 32x32 MFMA, dbuf, wave-private,
// counted-vmcnt pipeline, setprio, branch-free staging) all in 92-111us --
// the 2-phase-structure ceiling (m233); 8-phase escape needs N>=256 tiles
// which per-filter co=64 cannot form.
template<int K> struct KG {
    static constexpr int P     = (K - 1) / 2;
    static constexpr int NSEC  = (K + 7) / 8;          // kh sections
    static constexpr int SEGS  = 3 * K;                // octet-segments per section
    static constexpr int NCHK  = (SEGS + 3) / 4;       // MFMA K-32 chunks per section
    static constexpr int NCHKP = ((NCHK + 3) / 4) * 4; // padded to 4 waves
    static constexpr int COLS  = 128 + K - 1;
    static constexpr int XPAD  = 128;
    static constexpr int XSE   = COLS * 24 + XPAD;
};
// max padded seg read: (NCHKP*4-1)*8 + 127*24 + 8 must stay inside XSE
static_assert(127 * 24 + (KG<55>::NCHKP * 4 - 1) * 8 + 8 <= KG<55>::XSE, "pad55");
static_assert(127 * 24 + (KG<11>::NCHKP * 4 - 1) * 8 + 8 <= KG<11>::XSE, "pad11");
static_assert(KG<55>::XSE * 2 <= 18432, "xs fits smem");

struct PtrArgs {
    const float* w[8];
    const float* bias[8];
    unsigned short* wpk[8];
    int cum[9];            // cumulative NSEC*NCHKP per filter
};

// ---------------- weight repack ----------------
template<int K>
__device__ void repack_body(const float* __restrict__ w, unsigned short* __restrict__ wpk, int t) {
    constexpr int NCHKP = KG<K>::NCHKP;
    const int sec = t / NCHKP;
    const int tc  = t - sec * NCHKP;
    const int tid = threadIdx.x;
    const int co  = ((tid >> 6) << 4) + (tid & 15);
    const int seg = tc * 4 + ((tid >> 4) & 3);
    int kw = 0, r = 0;
    const bool vseg = seg < KG<K>::SEGS;
    if (vseg) { kw = seg / 3; r = seg - kw * 3; }
    short8 o;
    #pragma unroll
    for (int j = 0; j < 8; ++j) {
        const int icr = r * 8 + j;
        const int ic  = icr >> 3;
        const int kh  = sec * 8 + (icr & 7);
        float v = 0.f;
        if (vseg && kh < K)
            v = w[((co * 3 + ic) * K + kh) * K + kw];
        o[j] = (short)f2bf(v);
    }
    *reinterpret_cast<short8*>(wpk + ((size_t)(t * 256 + tid)) * 8) = o;
}

__global__ __launch_bounds__(256) void repack_all(PtrArgs a) {
    const int blk = blockIdx.x;
    int f = 0;
    #pragma unroll
    for (int i = 0; i < 8; ++i) if (blk >= a.cum[i + 1]) f = i + 1;
    const int t = blk - a.cum[f];
    switch (f) {
        case 0: repack_body< 3>(a.w[0], a.wpk[0], t); break;
        case 1: repack_body< 5>(a.w[1], a.wpk[1], t); break;
        case 2: repack_body< 7>(a.w[2], a.wpk[2], t); break;
        case 3: repack_body<11>(a.w[3], a.wpk[3], t); break;
        case 4: repack_body<15>(a.w[4], a.wpk[4], t); break;
        case 5: repack_body<23>(a.w[5], a.wpk[5], t); break;
        case 6: repack_body<37>(a.w[6], a.wpk[6], t); break;
        case 7: repack_body<55>(a.w[7], a.wpk[7], t); break;
    }
}

// -------- conv: 256 thr, 4 waves; wave = 64co x 128px x (1/4 of K-chunks) --------
#define MFMA_BF16 __builtin_amdgcn_mfma_f32_16x16x32_bf16

template<int K>
__device__ void conv_body(const float* __restrict__ x, const unsigned short* __restrict__ wpk,
                          const float* __restrict__ bias, unsigned short* __restrict__ feat,
                          int cbase, char* smem, int bx)
{
    constexpr int P     = KG<K>::P;
    constexpr int NCHKP = KG<K>::NCHKP;
    constexpr int NSEC  = KG<K>::NSEC;
    constexpr int COLS  = KG<K>::COLS;

    unsigned short* xs = (unsigned short*)smem;
    float* red = (float*)smem;          // aliases xs; used only after xs is dead

    const int tid = threadIdx.x;
    const int b   = bx >> 7;            // batch
    const int h   = bx & 127;           // image row

    const int lane = tid & 63;
    const int wv   = tid >> 6;          // 0..3 -> K-chunk quarter
    const int ln15 = lane & 15;
    const int lg   = lane >> 4;         // k-octet 0..3

    // zero the pad region (tail-seg reads land here; stays zero while xs lives)
    for (int i = tid * 4; i < KG<K>::XPAD; i += 1024)
        *reinterpret_cast<short4v*>(xs + COLS * 24 + i) = short4v{0, 0, 0, 0};

    f32x4 acc[4][8] = {};               // [costrip][pxstrip]
    const float* xb = x + (size_t)b * 3 * HWPIX;

    for (int sec = 0; sec < NSEC; ++sec) {
        if (sec > 0) __syncthreads();   // all waves done reading previous section
        for (int e = tid * 4; e < 24 * COLS; e += 1024) {
            const int c  = e / 24;
            const int i0 = e - c * 24;
            const int col = c - P;
            short4v pk;
            #pragma unroll
            for (int j = 0; j < 4; ++j) {
                const int icr = i0 + j;
                const int ic  = icr >> 3;
                const int row = h + sec * 8 + (icr & 7) - P;
                float v = 0.f;
                if ((unsigned)row < 128u && (unsigned)col < 128u)
                    v = xb[ic * HWPIX + row * 128 + col];
                pk[j] = (short)f2bf(v);
            }
            *reinterpret_cast<short4v*>(xs + e) = pk;
        }
        __syncthreads();

        const unsigned short* ws = wpk + (size_t)sec * NCHKP * 2048 + lane * 8;
        for (int tt = 0; tt < NCHKP / 4; ++tt) {
            const int t = tt * 4 + wv;
            const unsigned short* ap = ws + (size_t)t * 2048;
            short8 a0 = *reinterpret_cast<const short8*>(ap);
            short8 a1 = *reinterpret_cast<const short8*>(ap + 512);
            short8 a2 = *reinterpret_cast<const short8*>(ap + 1024);
            short8 a3 = *reinterpret_cast<const short8*>(ap + 1536);
            const unsigned short* bp = xs + ln15 * 24 + lg * 8 + t * 32;
            short8 b0 = *reinterpret_cast<const short8*>(bp);
            short8 b1 = *reinterpret_cast<const short8*>(bp + 1 * 384);
            short8 b2 = *reinterpret_cast<const short8*>(bp + 2 * 384);
            short8 b3 = *reinterpret_cast<const short8*>(bp + 3 * 384);
            short8 b4 = *reinterpret_cast<const short8*>(bp + 4 * 384);
            short8 b5 = *reinterpret_cast<const short8*>(bp + 5 * 384);
            short8 b6 = *reinterpret_cast<const short8*>(bp + 6 * 384);
            short8 b7 = *reinterpret_cast<const short8*>(bp + 7 * 384);

            acc[0][0] = MFMA_BF16(a0, b0, acc[0][0], 0, 0, 0);
            acc[0][1] = MFMA_BF16(a0, b1, acc[0][1], 0, 0, 0);
            acc[0][2] = MFMA_BF16(a0, b2, acc[0][2], 0, 0, 0);
            acc[0][3] = MFMA_BF16(a0, b3, acc[0][3], 0, 0, 0);
            acc[0][4] = MFMA_BF16(a0, b4, acc[0][4], 0, 0, 0);
            acc[0][5] = MFMA_BF16(a0, b5, acc[0][5], 0, 0, 0);
            acc[0][6] = MFMA_BF16(a0, b6, acc[0][6], 0, 0, 0);
            acc[0][7] = MFMA_BF16(a0, b7, acc[0][7], 0, 0, 0);
            acc[1][0] = MFMA_BF16(a1, b0, acc[1][0], 0, 0, 0);
            acc[1][1] = MFMA_BF16(a1, b1, acc[1][1], 0, 0, 0);
            acc[1][2] = MFMA_BF16(a1, b2, acc[1][2], 0, 0, 0);
            acc[1][3] = MFMA_BF16(a1, b3, acc[1][3], 0, 0, 0);
            acc[1][4] = MFMA_BF16(a1, b4, acc[1][4], 0, 0, 0);
            acc[1][5] = MFMA_BF16(a1, b5, acc[1][5], 0, 0, 0);
            acc[1][6] = MFMA_BF16(a1, b6, acc[1][6], 0, 0, 0);
            acc[1][7] = MFMA_BF16(a1, b7, acc[1][7], 0, 0, 0);
            acc[2][0] = MFMA_BF16(a2, b0, acc[2][0], 0, 0, 0);
            acc[2][1] = MFMA_BF16(a2, b1, acc[2][1], 0, 0, 0);
            acc[2][2] = MFMA_BF16(a2, b2, acc[2][2], 0, 0, 0);
            acc[2][3] = MFMA_BF16(a2, b3, acc[2][3], 0, 0, 0);
            acc[2][4] = MFMA_BF16(a2, b4, acc[2][4], 0, 0, 0);
            acc[2][5] = MFMA_BF16(a2, b5, acc[2][5], 0, 0, 0);
            acc[2][6] = MFMA_BF16(a2, b6, acc[2][6], 0, 0, 0);
            acc[2][7] = MFMA_BF16(a2, b7, acc[2][7], 0, 0, 0);
            acc[3][0] = MFMA_BF16(a3, b0, acc[3][0], 0, 0, 0);
            acc[3][1] = MFMA_BF16(a3, b1, acc[3][1], 0, 0, 0);
            acc[3][2] = MFMA_BF16(a3, b2, acc[3][2], 0, 0, 0);
            acc[3][3] = MFMA_BF16(a3, b3, acc[3][3], 0, 0, 0);
            acc[3][4] = MFMA_BF16(a3, b4, acc[3][4], 0, 0, 0);
            acc[3][5] = MFMA_BF16(a3, b5, acc[3][5], 0, 0, 0);
            acc[3][6] = MFMA_BF16(a3, b6, acc[3][6], 0, 0, 0);
            acc[3][7] = MFMA_BF16(a3, b7, acc[3][7], 0, 0, 0);
        }
    }

    // ---- cross-wave reduction via LDS (xs dead after this barrier) ----
    __syncthreads();
    const float bv  = bias[tid >> 2];
    const int   eco = tid >> 2;          // 0..63
    const int   ep0 = (tid & 3) * 4;     // 0,4,8,12
    const size_t fbase = (((size_t)(b * NCH + cbase + eco)) << 14) + h * 128;

    #pragma unroll
    for (int q = 0; q < 8; ++q) {
        if (q > 0) __syncthreads();      // previous pass's reads done
        #pragma unroll
        for (int cs = 0; cs < 4; ++cs)
            #pragma unroll
            for (int i = 0; i < 4; ++i)
                red[(wv * 64 + cs * 16 + lg * 4 + i) * 18 + ln15] = acc[cs][q][i];
        __syncthreads();
        short4v o;
        #pragma unroll
        for (int j = 0; j < 4; ++j) {
            const int px = ep0 + j;
            float v = red[(0 * 64 + eco) * 18 + px] + red[(1 * 64 + eco) * 18 + px]
                    + red[(2 * 64 + eco) * 18 + px] + red[(3 * 64 + eco) * 18 + px];
            o[j] = (short)f2bf(fmaxf(v + bv, 0.f));
        }
        *reinterpret_cast<short4v*>(feat + fbase + q * 16 + ep0) = o;
    }
}

__global__ __launch_bounds__(256, 2) void conv_all(const float* __restrict__ x,
                                                   PtrArgs a, unsigned short* __restrict__ feat)
{
    __shared__ __align__(16) char smem[18432];   // max(xs 8992B, red 4*64*18*4B)
    // LPT dispatch: heaviest filter (K=55) first so it spreads over all CUs
    switch (7 - blockIdx.y) {
        case 0: conv_body< 3>(x, a.wpk[0], a.bias[0], feat, 0 * 64, smem, blockIdx.x); break;
        case 1: conv_body< 5>(x, a.wpk[1], a.bias[1], feat, 1 * 64, smem, blockIdx.x); break;
        case 2: conv_body< 7>(x, a.wpk[2], a.bias[2], feat, 2 * 64, smem, blockIdx.x); break;
        case 3: conv_body<11>(x, a.wpk[3], a.bias[3], feat, 3 * 64, smem, blockIdx.x); break;
        case 4: conv_body<15>(x, a.wpk[4], a.bias[4], feat, 4 * 64, smem, blockIdx.x); break;
        case 5: conv_body<23>(x, a.wpk[5], a.bias[5], feat, 5 * 64, smem, blockIdx.x); break;
        case 6: conv_body<37>(x, a.wpk[6], a.bias[6], feat, 6 * 64, smem, blockIdx.x); break;
        case 7: conv_body<55>(x, a.wpk[7], a.bias[7], feat, 7 * 64, smem, blockIdx.x); break;
    }
}

// ---------------- gram via MFMA (unchanged, passing since r4) ----------------
__global__ __launch_bounds__(256) void gram_mfma(
    const unsigned short* __restrict__ feat, const int* __restrict__ perm,
    float* __restrict__ part)
{
    __shared__ __align__(16) unsigned short tile[64 * 256];
    __shared__ int permch[64];

    const int bg = blockIdx.y, chunk = blockIdx.x;
    const int b = bg >> 3, gq = bg & 7;
    const int tid = threadIdx.x;

    if (tid < 64) permch[tid] = perm[gq * 64 + tid];
    __syncthreads();

    const int lane = tid & 63;
    const int wv   = tid >> 6;
    const int ln15 = lane & 15;
    const int kg   = lane >> 4;

    f32x4 acc[4] = {};
    const size_t pxbase = (size_t)chunk * 512;

    for (int p2 = 0; p2 < 2; ++p2) {
        {
            const int r0 = tid >> 5;        // 0..7
            const int g  = tid & 31;        // 16B group 0..31
            #pragma unroll
            for (int it = 0; it < 8; ++it) {
                const int r = it * 8 + r0;
                const unsigned short* src =
                    feat + (((size_t)(b * NCH + permch[r])) << 14) + pxbase + p2 * 256 + g * 8;
                short8 v = *reinterpret_cast<const short8*>(src);
                *reinterpret_cast<short8*>(tile + r * 256 + ((g ^ (r & 7)) * 8)) = v;
            }
        }
        __syncthreads();
        #pragma unroll
        for (int t = 0; t < 8; ++t) {
            const int g  = t * 4 + kg;
            const int ra = wv * 16 + ln15;
            short8 av = *reinterpret_cast<const short8*>(tile + ra * 256 + ((g ^ (ra & 7)) * 8));
            #pragma unroll
            for (int cs = 0; cs < 4; ++cs) {
                const int rb = cs * 16 + ln15;
                short8 bv = *reinterpret_cast<const short8*>(tile + rb * 256 + ((g ^ (rb & 7)) * 8));
                acc[cs] = MFMA_BF16(av, bv, acc[cs], 0, 0, 0);
            }
        }
        __syncthreads();
    }

    float* pp = part + ((size_t)bg * GCHK + chunk) * 4096;
    #pragma unroll
    for (int cs = 0; cs < 4; ++cs)
        #pragma unroll
        for (int i = 0; i < 4; ++i) {
            const int row = wv * 16 + kg * 4 + i;
            const int col = cs * 16 + ln15;
            pp[row * 64 + col] = acc[cs][i];
        }
}

__global__ __launch_bounds__(256) void gram_reduce(
    const float* __restrict__ part, float* __restrict__ out)
{
    const int idx = blockIdx.x * 256 + threadIdx.x;   // 0..65535
    const int bg  = idx >> 12;
    const int e   = idx & 4095;
    const float* p = part + (size_t)bg * GCHK * 4096 + e;
    float s = 0.f;
    #pragma unroll
    for (int c = 0; c < GCHK; ++c) s += p[c * 4096];
    out[idx] = s;
}

extern "C" void kernel_launch(void* const* d_in, const int* in_sizes, int n_in,
                              void* d_out, int out_size, void* d_ws, size_t ws_size,
                              hipStream_t stream) {
    const float* x = (const float*)d_in[0];
    const int* perm = (const int*)d_in[17];

    // ws: feat bf16 32MiB | part 8MiB | wpk 572 chunks * 4KiB = 2.29MiB
    unsigned short* feat = (unsigned short*)d_ws;
    float* part = (float*)((char*)d_ws + (size_t)2 * NCH * HWPIX * sizeof(unsigned short));
    unsigned short* wpk0 = (unsigned short*)((char*)part + (size_t)16 * GCHK * 4096 * sizeof(float));
    float* out = (float*)d_out;

    const int nchk[8] = { KG<3>::NSEC * KG<3>::NCHKP,  KG<5>::NSEC * KG<5>::NCHKP,
                          KG<7>::NSEC * KG<7>::NCHKP,  KG<11>::NSEC * KG<11>::NCHKP,
                          KG<15>::NSEC * KG<15>::NCHKP, KG<23>::NSEC * KG<23>::NCHKP,
                          KG<37>::NSEC * KG<37>::NCHKP, KG<55>::NSEC * KG<55>::NCHKP };
    PtrArgs a;
    int acc = 0;
    for (int i = 0; i < 8; ++i) {
        a.w[i]    = (const float*)d_in[1 + 2 * i];
        a.bias[i] = (const float*)d_in[2 + 2 * i];
        a.wpk[i]  = wpk0 + (size_t)acc * 2048;
        a.cum[i]  = acc;
        acc += nchk[i];
    }
    a.cum[8] = acc;   // 572 total chunk-sections

    repack_all<<<acc, 256, 0, stream>>>(a);
    conv_all<<<dim3(256, 8), 256, 0, stream>>>(x, a, feat);
    gram_mfma<<<dim3(GCHK, 16), 256, 0, stream>>>(feat, perm, part);
    gram_reduce<<<dim3(65536 / 256), 256, 0, stream>>>(part, out);
}